// Round 2
// baseline (14088.910 us; speedup 1.0000x reference)
//
#include <hip/hip_runtime.h>
#include <stdint.h>

// ---------- types / helpers ----------
using short8  = __attribute__((ext_vector_type(8))) short;
using float4v = __attribute__((ext_vector_type(4))) float;

__device__ __forceinline__ float b2f(unsigned short u) {
    union { unsigned int i; float f; } v; v.i = ((unsigned int)u) << 16; return v.f;
}
__device__ __forceinline__ unsigned short f2b(float f) {
    union { float f; unsigned int i; } v; v.f = f;
    unsigned int x = v.i;
    unsigned int r = (x + 0x7fffu + ((x >> 16) & 1u)) >> 16;   // RNE
    return (unsigned short)r;
}

__device__ __forceinline__ void gload_lds16(const void* g, void* l) {
    // async global->LDS, 16B/lane; LDS dest = wave-uniform base + lane*16
    __builtin_amdgcn_global_load_lds((const __attribute__((address_space(1))) void*)g,
                                     (__attribute__((address_space(3))) void*)l, 16, 0, 0);
}

// ---------- degree counts ----------
__global__ void count_deg(const int* __restrict__ src, const int* __restrict__ dst,
                          float* __restrict__ cnt_h, float* __restrict__ cnt_b, int E) {
    int e = blockIdx.x * blockDim.x + threadIdx.x;
    if (e < E) {
        unsafeAtomicAdd(cnt_h + src[e], 1.0f);
        unsafeAtomicAdd(cnt_b + dst[e], 1.0f);
    }
}

// ---------- f32 -> bf16 elementwise convert (4 per thread) ----------
__global__ void cvt_to_bf16(const float* __restrict__ in, unsigned short* __restrict__ out,
                            size_t n4) {
    size_t t = (size_t)blockIdx.x * blockDim.x + threadIdx.x;
    if (t >= n4) return;
    const float4 v = *(const float4*)(in + t * 4);
    ushort4 u;
    u.x = f2b(v.x); u.y = f2b(v.y); u.z = f2b(v.z); u.w = f2b(v.w);
    *(ushort4*)(out + t * 4) = u;
}

// ---------- scatter-sum, d=128, f32 input: one wave per edge ----------
__global__ void scatter_f32_d128(const float* __restrict__ x,
                                 const int* __restrict__ gidx, const int* __restrict__ sidx,
                                 float* __restrict__ agg, int E) {
    int wid  = (blockIdx.x * blockDim.x + threadIdx.x) >> 6;
    int lane = threadIdx.x & 63;
    if (wid >= E) return;
    int g = gidx[wid];
    int s = sidx[wid];
    const float2 u = *(const float2*)(x + (size_t)g * 128 + lane * 2);
    float* ap = agg + (size_t)s * 128 + lane * 2;
    unsafeAtomicAdd(ap + 0, u.x);
    unsafeAtomicAdd(ap + 1, u.y);
}

// ---------- scatter-sum, d=256, bf16 input: one wave per edge ----------
__global__ void scatter_bf16_d256(const unsigned short* __restrict__ x,
                                  const int* __restrict__ gidx, const int* __restrict__ sidx,
                                  float* __restrict__ agg, int E) {
    int wid  = (blockIdx.x * blockDim.x + threadIdx.x) >> 6;
    int lane = threadIdx.x & 63;
    if (wid >= E) return;
    int g = gidx[wid];
    int s = sidx[wid];
    const ushort4 u = *(const ushort4*)(x + (size_t)g * 256 + lane * 4);
    float* ap = agg + (size_t)s * 256 + lane * 4;
    unsafeAtomicAdd(ap + 0, b2f(u.x));
    unsafeAtomicAdd(ap + 1, b2f(u.y));
    unsafeAtomicAdd(ap + 2, b2f(u.z));
    unsafeAtomicAdd(ap + 3, b2f(u.w));
}

// ---------- normalize by degree + convert to bf16 ----------
template <int D>
__global__ void normalize_cvt(const float* __restrict__ agg, const float* __restrict__ cnt,
                              unsigned short* __restrict__ out, int N) {
    const int G = D / 8;                       // 8 elems per thread
    int t = blockIdx.x * blockDim.x + threadIdx.x;
    int i = t / G;
    if (i >= N) return;
    int jg = t - i * G;
    float inv = 1.0f / fmaxf(cnt[i], 1.0f);
    const float* ap = agg + (size_t)i * D + jg * 8;
    float4 a0 = *(const float4*)ap;
    float4 a1 = *(const float4*)(ap + 4);
    union { unsigned short s[8]; uint4 v; } u;
    u.s[0] = f2b(a0.x * inv); u.s[1] = f2b(a0.y * inv);
    u.s[2] = f2b(a0.z * inv); u.s[3] = f2b(a0.w * inv);
    u.s[4] = f2b(a1.x * inv); u.s[5] = f2b(a1.y * inv);
    u.s[6] = f2b(a1.z * inv); u.s[7] = f2b(a1.w * inv);
    *(uint4*)(out + (size_t)i * D + jg * 8) = u.v;
}

// ---------- weight transpose + convert: W f32 [K][256] -> Wt bf16 [256][K] ----------
__global__ void transpose_w(const float* __restrict__ W,
                            unsigned short* __restrict__ Wt, int K) {
    int k = blockIdx.x;        // [0,K)
    int c = threadIdx.x;       // [0,256)
    Wt[(size_t)c * K + k] = f2b(W[(size_t)k * 256 + c]);
}

// ---------- fused GEMM: res = relu(A0@B0^T + A1@B1^T + bias) ----------
// A0,A1: M x K bf16 (row-major, ld=K). B0,B1: 256 x K bf16 (transposed weights).
// F32OUT ? write f32 to outf : write bf16 to outb.
// Tile: BM=64 x BN=256, BK=64, 4 waves (wave tile 64x64).
template <bool F32OUT>
__global__ __launch_bounds__(256, 3)
void gemm_fused(const unsigned short* __restrict__ A0, const unsigned short* __restrict__ A1,
                const unsigned short* __restrict__ B0, const unsigned short* __restrict__ B1,
                const float* __restrict__ bias,
                float* __restrict__ outf, unsigned short* __restrict__ outb,
                int M, int K) {
    __shared__ unsigned short As[64 * 64];    // 8 KB
    __shared__ unsigned short Bs[256 * 64];   // 32 KB
    const int tid  = threadIdx.x;
    const int wave = tid >> 6, lane = tid & 63;
    const int wn   = wave;                     // wave covers cols [wn*64, wn*64+64)
    const int row0 = blockIdx.x * 64;

    float4v acc[4][4];
    #pragma unroll
    for (int i = 0; i < 4; ++i)
        #pragma unroll
        for (int j = 0; j < 4; ++j) acc[i][j] = (float4v){0.f, 0.f, 0.f, 0.f};

    const int r  = lane >> 3;     // 0..7  (row within 8-row group)
    const int cg = lane & 7;      // 0..7  (16B col group)
    const int kchunks = K >> 6;
    const int nchunks = kchunks * 2;

    for (int c = 0; c < nchunks; ++c) {
        const unsigned short* Aseg = (c < kchunks) ? A0 : A1;
        const unsigned short* Bseg = (c < kchunks) ? B0 : B1;
        const int k0 = ((c < kchunks) ? c : c - kchunks) << 6;

        if (c) __syncthreads();
        {   // stage A: 64 rows; 16 rows per wave = 2 instrs (guards are wave-uniform)
            int rr = wave * 16;
            const unsigned short* gp = Aseg + (size_t)(row0 + rr + r) * K + k0 + cg * 8;
            unsigned short* lp = As + rr * 64;
            if (row0 + rr + r < M)     gload_lds16(gp, lp);
            if (row0 + rr + 8 + r < M) gload_lds16(gp + 8 * (size_t)K, lp + 8 * 64);
        }
        {   // stage B: 256 rows; 64 rows per wave = 8 instrs
            int rr = wave * 64;
            const unsigned short* gp = Bseg + (size_t)(rr + r) * K + k0 + cg * 8;
            unsigned short* lp = Bs + rr * 64;
            #pragma unroll
            for (int i = 0; i < 8; ++i)
                gload_lds16(gp + (size_t)(i * 8) * K, lp + i * 8 * 64);
        }
        __syncthreads();

        const int q8 = (lane >> 4) * 8;
        const int l15 = lane & 15;
        #pragma unroll
        for (int kk = 0; kk <= 32; kk += 32) {
            short8 af[4], bf[4];
            #pragma unroll
            for (int f = 0; f < 4; ++f)
                af[f] = *(const short8*)(As + (f * 16 + l15) * 64 + kk + q8);
            #pragma unroll
            for (int f = 0; f < 4; ++f)
                bf[f] = *(const short8*)(Bs + (wn * 64 + f * 16 + l15) * 64 + kk + q8);
            #pragma unroll
            for (int fm = 0; fm < 4; ++fm)
                #pragma unroll
                for (int fn = 0; fn < 4; ++fn)
                    acc[fm][fn] = __builtin_amdgcn_mfma_f32_16x16x32_bf16(
                        af[fm], bf[fn], acc[fm][fn], 0, 0, 0);
        }
    }

    // epilogue: C/D layout col=lane&15, row=(lane>>4)*4+reg  [verified m89/m91]
    const int l15 = lane & 15;
    const int rq  = (lane >> 4) * 4;
    #pragma unroll
    for (int fn = 0; fn < 4; ++fn) {
        int col = wn * 64 + fn * 16 + l15;
        float bv = bias[col];
        #pragma unroll
        for (int fm = 0; fm < 4; ++fm) {
            #pragma unroll
            for (int rg = 0; rg < 4; ++rg) {
                int row = row0 + fm * 16 + rq + rg;
                if (row < M) {
                    float v = fmaxf(acc[fm][fn][rg] + bv, 0.0f);
                    if (F32OUT) outf[(size_t)row * 256 + col] = v;
                    else        outb[(size_t)row * 256 + col] = f2b(v);
                }
            }
        }
    }
}

// ---------- launcher ----------
extern "C" void kernel_launch(void* const* d_in, const int* in_sizes, int n_in,
                              void* d_out, int out_size, void* d_ws, size_t ws_size,
                              hipStream_t stream) {
    const int DIN = 128, H = 256;
    const int N = in_sizes[0] / DIN;
    const int E = in_sizes[2] / 2;

    const float* xh = (const float*)d_in[0];
    const float* xb = (const float*)d_in[1];
    const int* ei  = (const int*)d_in[2];
    const int* src = ei;
    const int* dst = ei + E;
    const float* h1Wl = (const float*)d_in[3];
    const float* h1Wr = (const float*)d_in[4];
    const float* h1b  = (const float*)d_in[5];
    const float* h2Wl = (const float*)d_in[6];
    const float* h2Wr = (const float*)d_in[7];
    const float* h2b  = (const float*)d_in[8];
    const float* b1Wl = (const float*)d_in[9];
    const float* b1Wr = (const float*)d_in[10];
    const float* b1b  = (const float*)d_in[11];
    const float* b2Wl = (const float*)d_in[12];
    const float* b2Wr = (const float*)d_in[13];
    const float* b2b  = (const float*)d_in[14];

    float* outH = (float*)d_out;
    float* outB = outH + (size_t)N * H;

    // ws layout:
    //  cnt_h[N] f32 | cnt_b[N] f32 | Wt 8 mats bf16 | agg[N*256] f32 |
    //  slotA[N*256] bf16 (aggbf; layer1: aggbf1 in [0,N*128) + xbf in [N*128,N*256)) |
    //  hbf[N*256] bf16
    float* cnt_h = (float*)d_ws;
    float* cnt_b = cnt_h + N;
    unsigned short* wtp = (unsigned short*)(cnt_b + N);
    unsigned short* t_h1l = wtp; wtp += DIN * H;
    unsigned short* t_h1r = wtp; wtp += DIN * H;
    unsigned short* t_h2l = wtp; wtp += H * H;
    unsigned short* t_h2r = wtp; wtp += H * H;
    unsigned short* t_b1l = wtp; wtp += DIN * H;
    unsigned short* t_b1r = wtp; wtp += DIN * H;
    unsigned short* t_b2l = wtp; wtp += H * H;
    unsigned short* t_b2r = wtp; wtp += H * H;
    float* agg = (float*)wtp;
    unsigned short* slotA = (unsigned short*)(agg + (size_t)N * 256);
    unsigned short* aggbf = slotA;                       // aggbf1 (N*128) or aggbf2 (N*256)
    unsigned short* xbf   = slotA + (size_t)N * 128;     // layer-1 only
    unsigned short* hbf   = slotA + (size_t)N * 256;

    const int BLK = 256;
    dim3 blk(BLK);

    // degree counts (shared by both layers of each branch)
    hipMemsetAsync(cnt_h, 0, (size_t)2 * N * sizeof(float), stream);
    count_deg<<<dim3((E + BLK - 1) / BLK), blk, 0, stream>>>(src, dst, cnt_h, cnt_b, E);

    // weight transposes + bf16 convert (tiny)
    transpose_w<<<dim3(DIN), blk, 0, stream>>>(h1Wl, t_h1l, DIN);
    transpose_w<<<dim3(DIN), blk, 0, stream>>>(h1Wr, t_h1r, DIN);
    transpose_w<<<dim3(H),   blk, 0, stream>>>(h2Wl, t_h2l, H);
    transpose_w<<<dim3(H),   blk, 0, stream>>>(h2Wr, t_h2r, H);
    transpose_w<<<dim3(DIN), blk, 0, stream>>>(b1Wl, t_b1l, DIN);
    transpose_w<<<dim3(DIN), blk, 0, stream>>>(b1Wr, t_b1r, DIN);
    transpose_w<<<dim3(H),   blk, 0, stream>>>(b2Wl, t_b2l, H);
    transpose_w<<<dim3(H),   blk, 0, stream>>>(b2Wr, t_b2r, H);

    dim3 sgrid((E + 3) / 4);                       // wave per edge, 4 waves/block
    dim3 ggrid((N + 63) / 64);                     // GEMM: 64 rows per block
    int ng128 = ((size_t)N * (DIN / 8) + BLK - 1) / BLK;
    int ng256 = ((size_t)N * (H   / 8) + BLK - 1) / BLK;
    int ncvt  = ((size_t)N * DIN / 4 + BLK - 1) / BLK;

    // ---- human branch: gather at dst, scatter to src, counts = cnt_h ----
    cvt_to_bf16<<<dim3(ncvt), blk, 0, stream>>>(xh, xbf, (size_t)N * DIN / 4);
    hipMemsetAsync(agg, 0, (size_t)N * DIN * sizeof(float), stream);
    scatter_f32_d128<<<sgrid, blk, 0, stream>>>(xh, dst, src, agg, E);
    normalize_cvt<128><<<dim3(ng128), blk, 0, stream>>>(agg, cnt_h, aggbf, N);
    gemm_fused<false><<<ggrid, blk, 0, stream>>>(aggbf, xbf, t_h1l, t_h1r, h1b,
                                                 nullptr, hbf, N, DIN);

    hipMemsetAsync(agg, 0, (size_t)N * H * sizeof(float), stream);
    scatter_bf16_d256<<<sgrid, blk, 0, stream>>>(hbf, dst, src, agg, E);
    normalize_cvt<256><<<dim3(ng256), blk, 0, stream>>>(agg, cnt_h, aggbf, N);
    gemm_fused<true><<<ggrid, blk, 0, stream>>>(aggbf, hbf, t_h2l, t_h2r, h2b,
                                                outH, nullptr, N, H);

    // ---- bacterial branch: gather at src, scatter to dst, counts = cnt_b ----
    cvt_to_bf16<<<dim3(ncvt), blk, 0, stream>>>(xb, xbf, (size_t)N * DIN / 4);
    hipMemsetAsync(agg, 0, (size_t)N * DIN * sizeof(float), stream);
    scatter_f32_d128<<<sgrid, blk, 0, stream>>>(xb, src, dst, agg, E);
    normalize_cvt<128><<<dim3(ng128), blk, 0, stream>>>(agg, cnt_b, aggbf, N);
    gemm_fused<false><<<ggrid, blk, 0, stream>>>(aggbf, xbf, t_b1l, t_b1r, b1b,
                                                 nullptr, hbf, N, DIN);

    hipMemsetAsync(agg, 0, (size_t)N * H * sizeof(float), stream);
    scatter_bf16_d256<<<sgrid, blk, 0, stream>>>(hbf, src, dst, agg, E);
    normalize_cvt<256><<<dim3(ng256), blk, 0, stream>>>(agg, cnt_b, aggbf, N);
    gemm_fused<true><<<ggrid, blk, 0, stream>>>(aggbf, hbf, t_b2l, t_b2r, b2b,
                                                outB, nullptr, N, H);
}

// Round 3
// 1504.421 us; speedup vs baseline: 9.3650x; 9.3650x over previous
//
#include <hip/hip_runtime.h>
#include <stdint.h>

// ---------- types / helpers ----------
using short8  = __attribute__((ext_vector_type(8))) short;
using float4v = __attribute__((ext_vector_type(4))) float;

__device__ __forceinline__ float b2f(unsigned short u) {
    union { unsigned int i; float f; } v; v.i = ((unsigned int)u) << 16; return v.f;
}
__device__ __forceinline__ unsigned short f2b(float f) {
    union { float f; unsigned int i; } v; v.f = f;
    unsigned int x = v.i;
    unsigned int r = (x + 0x7fffu + ((x >> 16) & 1u)) >> 16;   // RNE
    return (unsigned short)r;
}

__device__ __forceinline__ void gload_lds16(const void* g, void* l) {
    // async global->LDS, 16B/lane; LDS dest = wave-uniform base + lane*16
    __builtin_amdgcn_global_load_lds((const __attribute__((address_space(1))) void*)g,
                                     (__attribute__((address_space(3))) void*)l, 16, 0, 0);
}

// ---------- int degree counts (human keyed by src, bact keyed by dst) ----------
__global__ void count_deg(const int* __restrict__ src, const int* __restrict__ dst,
                          int* __restrict__ deg_h, int* __restrict__ deg_b, int E) {
    int e = blockIdx.x * blockDim.x + threadIdx.x;
    if (e < E) {
        atomicAdd(deg_h + src[e], 1);
        atomicAdd(deg_b + dst[e], 1);
    }
}

// ---------- 3-kernel exclusive scan over deg[N] -> row[N+1] ----------
// scan1: per-1024-chunk sums
__global__ void scan1(const int* __restrict__ deg, int* __restrict__ partial, int N) {
    int t = threadIdx.x;
    int base = blockIdx.x * 1024 + t * 4;
    int s = 0;
    #pragma unroll
    for (int i = 0; i < 4; ++i) { int idx = base + i; if (idx < N) s += deg[idx]; }
    #pragma unroll
    for (int off = 32; off; off >>= 1) s += __shfl_down(s, off);
    __shared__ int sm[4];
    if ((t & 63) == 0) sm[t >> 6] = s;
    __syncthreads();
    if (t == 0) partial[blockIdx.x] = sm[0] + sm[1] + sm[2] + sm[3];
}
// scan2: exclusive scan of P partials (P ~ 98), single thread
__global__ void scan2(int* __restrict__ partial, int P) {
    if (blockIdx.x == 0 && threadIdx.x == 0) {
        int run = 0;
        for (int i = 0; i < P; ++i) { int v = partial[i]; partial[i] = run; run += v; }
    }
}
// scan3: per-chunk exclusive scan + chunk offset -> row; also row[N]=E
__global__ void scan3(const int* __restrict__ deg, const int* __restrict__ partial,
                      int* __restrict__ row, int N, int E) {
    int t = threadIdx.x;
    int lane = t & 63, wv = t >> 6;
    int base = blockIdx.x * 1024 + t * 4;
    int d[4]; int s = 0;
    #pragma unroll
    for (int i = 0; i < 4; ++i) { int idx = base + i; d[i] = (idx < N) ? deg[idx] : 0; s += d[i]; }
    int inc = s;
    #pragma unroll
    for (int off = 1; off < 64; off <<= 1) { int v = __shfl_up(inc, off); if (lane >= off) inc += v; }
    __shared__ int wsum[4];
    if (lane == 63) wsum[wv] = inc;
    __syncthreads();
    int woff = 0;
    for (int w = 0; w < wv; ++w) woff += wsum[w];
    int run = inc - s + woff + partial[blockIdx.x];
    #pragma unroll
    for (int i = 0; i < 4; ++i) { int idx = base + i; if (idx < N) row[idx] = run; run += d[i]; }
    if (blockIdx.x == 0 && t == 0) row[N] = E;
}

// ---------- bucket fill: adj_h (by src, stores dst), adj_b (by dst, stores src) ----------
__global__ void fill_adj(const int* __restrict__ src, const int* __restrict__ dst,
                         int* __restrict__ cur_h, int* __restrict__ cur_b,
                         int* __restrict__ adj_h, int* __restrict__ adj_b, int E) {
    int e = blockIdx.x * blockDim.x + threadIdx.x;
    if (e < E) {
        int s = src[e], d = dst[e];
        adj_h[atomicAdd(cur_h + s, 1)] = d;
        adj_b[atomicAdd(cur_b + d, 1)] = s;
    }
}

// ---------- f32 -> bf16 elementwise convert (4 per thread) ----------
__global__ void cvt_to_bf16(const float* __restrict__ in, unsigned short* __restrict__ out,
                            size_t n4) {
    size_t t = (size_t)blockIdx.x * blockDim.x + threadIdx.x;
    if (t >= n4) return;
    const float4 v = *(const float4*)(in + t * 4);
    ushort4 u;
    u.x = f2b(v.x); u.y = f2b(v.y); u.z = f2b(v.z); u.w = f2b(v.w);
    *(ushort4*)(out + t * 4) = u;
}

// ---------- CSR gather + mean + bf16 out: one wave per node ----------
template <int D>   // 128 (2 elems/lane) or 256 (4 elems/lane)
__global__ __launch_bounds__(256)
void gather_mean(const unsigned short* __restrict__ x, const int* __restrict__ row,
                 const int* __restrict__ adj, unsigned short* __restrict__ out, int N) {
    const int PL = D / 64;
    int wid  = (blockIdx.x * blockDim.x + threadIdx.x) >> 6;
    int lane = threadIdx.x & 63;
    if (wid >= N) return;
    int beg = row[wid];
    int deg = row[wid + 1] - beg;

    float acc[PL];
    #pragma unroll
    for (int p = 0; p < PL; ++p) acc[p] = 0.0f;

    for (int base = 0; base < deg; base += 64) {
        int nb_l = (base + lane < deg) ? adj[beg + base + lane] : 0;
        int m = deg - base; if (m > 64) m = 64;
        for (int j = 0; j < m; ++j) {
            int nb = __shfl(nb_l, j);
            const unsigned short* xp = x + (size_t)nb * D + lane * PL;
            if (PL == 2) {
                ushort2 u = *(const ushort2*)xp;
                acc[0] += b2f(u.x); acc[1] += b2f(u.y);
            } else {
                ushort4 u = *(const ushort4*)xp;
                acc[0] += b2f(u.x); acc[1] += b2f(u.y);
                acc[2] += b2f(u.z); acc[3] += b2f(u.w);
            }
        }
    }
    float inv = 1.0f / (float)((deg > 0) ? deg : 1);
    unsigned short* op = out + (size_t)wid * D + lane * PL;
    if (PL == 2) {
        ushort2 u; u.x = f2b(acc[0] * inv); u.y = f2b(acc[1] * inv);
        *(ushort2*)op = u;
    } else {
        ushort4 u;
        u.x = f2b(acc[0] * inv); u.y = f2b(acc[1] * inv);
        u.z = f2b(acc[2] * inv); u.w = f2b(acc[3] * inv);
        *(ushort4*)op = u;
    }
}

// ---------- weight transpose + convert: W f32 [K][256] -> Wt bf16 [256][K] ----------
__global__ void transpose_w(const float* __restrict__ W,
                            unsigned short* __restrict__ Wt, int K) {
    int k = blockIdx.x;        // [0,K)
    int c = threadIdx.x;       // [0,256)
    Wt[(size_t)c * K + k] = f2b(W[(size_t)k * 256 + c]);
}

// ---------- fused GEMM: res = relu(A0@B0^T + A1@B1^T + bias) ----------
// A0,A1: M x K bf16 (row-major). B0,B1: 256 x K bf16 (transposed weights).
// Tile: BM=64 x BN=256, BK=64, 4 waves (wave tile 64x64).
template <bool F32OUT>
__global__ __launch_bounds__(256, 3)
void gemm_fused(const unsigned short* __restrict__ A0, const unsigned short* __restrict__ A1,
                const unsigned short* __restrict__ B0, const unsigned short* __restrict__ B1,
                const float* __restrict__ bias,
                float* __restrict__ outf, unsigned short* __restrict__ outb,
                int M, int K) {
    __shared__ unsigned short As[64 * 64];    // 8 KB
    __shared__ unsigned short Bs[256 * 64];   // 32 KB
    const int tid  = threadIdx.x;
    const int wave = tid >> 6, lane = tid & 63;
    const int wn   = wave;
    const int row0 = blockIdx.x * 64;

    float4v acc[4][4];
    #pragma unroll
    for (int i = 0; i < 4; ++i)
        #pragma unroll
        for (int j = 0; j < 4; ++j) acc[i][j] = (float4v){0.f, 0.f, 0.f, 0.f};

    const int r  = lane >> 3;
    const int cg = lane & 7;
    const int kchunks = K >> 6;
    const int nchunks = kchunks * 2;

    for (int c = 0; c < nchunks; ++c) {
        const unsigned short* Aseg = (c < kchunks) ? A0 : A1;
        const unsigned short* Bseg = (c < kchunks) ? B0 : B1;
        const int k0 = ((c < kchunks) ? c : c - kchunks) << 6;

        if (c) __syncthreads();
        {   // stage A: 64 rows; 16 rows per wave
            int rr = wave * 16;
            const unsigned short* gp = Aseg + (size_t)(row0 + rr + r) * K + k0 + cg * 8;
            unsigned short* lp = As + rr * 64;
            if (row0 + rr + r < M)     gload_lds16(gp, lp);
            if (row0 + rr + 8 + r < M) gload_lds16(gp + 8 * (size_t)K, lp + 8 * 64);
        }
        {   // stage B: 256 rows; 64 rows per wave
            int rr = wave * 64;
            const unsigned short* gp = Bseg + (size_t)(rr + r) * K + k0 + cg * 8;
            unsigned short* lp = Bs + rr * 64;
            #pragma unroll
            for (int i = 0; i < 8; ++i)
                gload_lds16(gp + (size_t)(i * 8) * K, lp + i * 8 * 64);
        }
        __syncthreads();

        const int q8 = (lane >> 4) * 8;
        const int l15 = lane & 15;
        #pragma unroll
        for (int kk = 0; kk <= 32; kk += 32) {
            short8 af[4], bf[4];
            #pragma unroll
            for (int f = 0; f < 4; ++f)
                af[f] = *(const short8*)(As + (f * 16 + l15) * 64 + kk + q8);
            #pragma unroll
            for (int f = 0; f < 4; ++f)
                bf[f] = *(const short8*)(Bs + (wn * 64 + f * 16 + l15) * 64 + kk + q8);
            #pragma unroll
            for (int fm = 0; fm < 4; ++fm)
                #pragma unroll
                for (int fn = 0; fn < 4; ++fn)
                    acc[fm][fn] = __builtin_amdgcn_mfma_f32_16x16x32_bf16(
                        af[fm], bf[fn], acc[fm][fn], 0, 0, 0);
        }
    }

    // epilogue: C/D layout col=lane&15, row=(lane>>4)*4+reg  [verified m89/m91]
    const int l15 = lane & 15;
    const int rq  = (lane >> 4) * 4;
    #pragma unroll
    for (int fn = 0; fn < 4; ++fn) {
        int col = wn * 64 + fn * 16 + l15;
        float bv = bias[col];
        #pragma unroll
        for (int fm = 0; fm < 4; ++fm) {
            #pragma unroll
            for (int rg = 0; rg < 4; ++rg) {
                int row = row0 + fm * 16 + rq + rg;
                if (row < M) {
                    float v = fmaxf(acc[fm][fn][rg] + bv, 0.0f);
                    if (F32OUT) outf[(size_t)row * 256 + col] = v;
                    else        outb[(size_t)row * 256 + col] = f2b(v);
                }
            }
        }
    }
}

// ---------- launcher ----------
extern "C" void kernel_launch(void* const* d_in, const int* in_sizes, int n_in,
                              void* d_out, int out_size, void* d_ws, size_t ws_size,
                              hipStream_t stream) {
    const int DIN = 128, H = 256;
    const int N = in_sizes[0] / DIN;
    const int E = in_sizes[2] / 2;

    const float* xh = (const float*)d_in[0];
    const float* xb = (const float*)d_in[1];
    const int* ei  = (const int*)d_in[2];
    const int* src = ei;
    const int* dst = ei + E;
    const float* h1Wl = (const float*)d_in[3];
    const float* h1Wr = (const float*)d_in[4];
    const float* h1b  = (const float*)d_in[5];
    const float* h2Wl = (const float*)d_in[6];
    const float* h2Wr = (const float*)d_in[7];
    const float* h2b  = (const float*)d_in[8];
    const float* b1Wl = (const float*)d_in[9];
    const float* b1Wr = (const float*)d_in[10];
    const float* b1b  = (const float*)d_in[11];
    const float* b2Wl = (const float*)d_in[12];
    const float* b2Wr = (const float*)d_in[13];
    const float* b2b  = (const float*)d_in[14];

    float* outH = (float*)d_out;
    float* outB = outH + (size_t)N * H;

    // ---- ws layout ----
    // ints: deg_h[N] deg_b[N] row_h[N+1] row_b[N+1] cur_h[N] cur_b[N] partial[256] adj_h[E] adj_b[E]
    // bf16: Wt (8 mats) | xbf[N*128] | aggbf[N*256] | hbf[N*256]
    int* deg_h = (int*)d_ws;
    int* deg_b = deg_h + N;
    int* row_h = deg_b + N;
    int* row_b = row_h + (N + 1);
    int* cur_h = row_b + (N + 1);
    int* cur_b = cur_h + N;
    int* partial = cur_b + N;          // up to 256 chunk sums
    int* adj_h = partial + 256;
    int* adj_b = adj_h + E;
    unsigned short* wtp = (unsigned short*)(adj_b + E);
    unsigned short* t_h1l = wtp; wtp += DIN * H;
    unsigned short* t_h1r = wtp; wtp += DIN * H;
    unsigned short* t_h2l = wtp; wtp += H * H;
    unsigned short* t_h2r = wtp; wtp += H * H;
    unsigned short* t_b1l = wtp; wtp += DIN * H;
    unsigned short* t_b1r = wtp; wtp += DIN * H;
    unsigned short* t_b2l = wtp; wtp += H * H;
    unsigned short* t_b2r = wtp; wtp += H * H;
    unsigned short* xbf   = wtp;
    unsigned short* aggbf = xbf + (size_t)N * DIN;
    unsigned short* hbf   = aggbf + (size_t)N * H;

    const int BLK = 256;
    dim3 blk(BLK);
    const int P = (N + 1023) / 1024;   // scan chunks (<=256 for N<=262144)

    // ---- build CSRs (shared by both layers of each branch) ----
    hipMemsetAsync(deg_h, 0, (size_t)2 * N * sizeof(int), stream);
    count_deg<<<dim3((E + BLK - 1) / BLK), blk, 0, stream>>>(src, dst, deg_h, deg_b, E);

    scan1<<<dim3(P), blk, 0, stream>>>(deg_h, partial, N);
    scan2<<<dim3(1), blk, 0, stream>>>(partial, P);
    scan3<<<dim3(P), blk, 0, stream>>>(deg_h, partial, row_h, N, E);
    scan1<<<dim3(P), blk, 0, stream>>>(deg_b, partial, N);
    scan2<<<dim3(1), blk, 0, stream>>>(partial, P);
    scan3<<<dim3(P), blk, 0, stream>>>(deg_b, partial, row_b, N, E);

    hipMemcpyAsync(cur_h, row_h, (size_t)N * sizeof(int), hipMemcpyDeviceToDevice, stream);
    hipMemcpyAsync(cur_b, row_b, (size_t)N * sizeof(int), hipMemcpyDeviceToDevice, stream);
    fill_adj<<<dim3((E + BLK - 1) / BLK), blk, 0, stream>>>(src, dst, cur_h, cur_b,
                                                            adj_h, adj_b, E);

    // ---- weight transposes + bf16 convert (tiny) ----
    transpose_w<<<dim3(DIN), blk, 0, stream>>>(h1Wl, t_h1l, DIN);
    transpose_w<<<dim3(DIN), blk, 0, stream>>>(h1Wr, t_h1r, DIN);
    transpose_w<<<dim3(H),   blk, 0, stream>>>(h2Wl, t_h2l, H);
    transpose_w<<<dim3(H),   blk, 0, stream>>>(h2Wr, t_h2r, H);
    transpose_w<<<dim3(DIN), blk, 0, stream>>>(b1Wl, t_b1l, DIN);
    transpose_w<<<dim3(DIN), blk, 0, stream>>>(b1Wr, t_b1r, DIN);
    transpose_w<<<dim3(H),   blk, 0, stream>>>(b2Wl, t_b2l, H);
    transpose_w<<<dim3(H),   blk, 0, stream>>>(b2Wr, t_b2r, H);

    dim3 nggrid((N + 3) / 4);                      // gather: wave per node, 4 waves/block
    dim3 ggrid((N + 63) / 64);                     // GEMM: 64 rows per block
    int ncvt = ((size_t)N * DIN / 4 + BLK - 1) / BLK;

    // ---- human branch: CSR keyed by src, neighbors are dst ----
    cvt_to_bf16<<<dim3(ncvt), blk, 0, stream>>>(xh, xbf, (size_t)N * DIN / 4);
    gather_mean<128><<<nggrid, blk, 0, stream>>>(xbf, row_h, adj_h, aggbf, N);
    gemm_fused<false><<<ggrid, blk, 0, stream>>>(aggbf, xbf, t_h1l, t_h1r, h1b,
                                                 nullptr, hbf, N, DIN);
    gather_mean<256><<<nggrid, blk, 0, stream>>>(hbf, row_h, adj_h, aggbf, N);
    gemm_fused<true><<<ggrid, blk, 0, stream>>>(aggbf, hbf, t_h2l, t_h2r, h2b,
                                                outH, nullptr, N, H);

    // ---- bacterial branch: CSR keyed by dst, neighbors are src ----
    cvt_to_bf16<<<dim3(ncvt), blk, 0, stream>>>(xb, xbf, (size_t)N * DIN / 4);
    gather_mean<128><<<nggrid, blk, 0, stream>>>(xbf, row_b, adj_b, aggbf, N);
    gemm_fused<false><<<ggrid, blk, 0, stream>>>(aggbf, xbf, t_b1l, t_b1r, b1b,
                                                 nullptr, hbf, N, DIN);
    gather_mean<256><<<nggrid, blk, 0, stream>>>(hbf, row_b, adj_b, aggbf, N);
    gemm_fused<true><<<ggrid, blk, 0, stream>>>(aggbf, hbf, t_b2l, t_b2r, b2b,
                                                outB, nullptr, N, H);
}